// Round 14
// baseline (427.539 us; speedup 1.0000x reference)
//
#include <hip/hip_runtime.h>
#include <math.h>

typedef __bf16 bf16x8 __attribute__((ext_vector_type(8)));
typedef float f32x4 __attribute__((ext_vector_type(4)));
typedef unsigned short u16;
typedef unsigned short u16x8 __attribute__((ext_vector_type(8)));
typedef unsigned int u32;

constexpr int BATCH = 2048;
constexpr int ROWS  = 4096;   // 2 steps x 2048
constexpr int HID   = 512;
constexpr int NACT  = 8;
constexpr int NFB   = 512;    // fused grid: 2 blocks/CU, all co-resident

__device__ __forceinline__ float gelu_f(float x) {
    return 0.5f * x * (1.0f + erff(x * 0.70710678118654752f));
}
__device__ __forceinline__ u16 f2bf(float f) {
    u32 u = __float_as_uint(f);
    return (u16)((u + 0x7FFFu + ((u >> 16) & 1u)) >> 16);
}
__device__ __forceinline__ float bf2f(u16 h) {
    return __uint_as_float(((u32)h) << 16);
}

// Fragment-chunk layout (round-10 proven): plane[(r>>4)*16 + (k>>5)][512],
// idx = (((k&31)>>3)*16 + (r&15))*8 + (k&7). One 16-row x 32-k tile = one
// contiguous 1KB block in exact MFMA lane order.
__device__ __forceinline__ size_t fragoff(int r, int k) {
    return (size_t)(((r >> 4) * 16 + (k >> 5)) * 512
                    + (((k & 31) >> 3) * 16 + (r & 15)) * 8 + (k & 7));
}

// ---------------------------------------------------------------------------
// K_prep: z<4 -> transpose + hi/lo-split weight layer z into wt (frag layout)
//         z==4 (x<4,y==0) -> partials[x] = temb-slice @ W_in slice.
//         Block (0,0,4) also zeroes the 8 grid-barrier slots (every launch ->
//         deterministic, poison-safe, graph-replay-safe).
// ---------------------------------------------------------------------------
__global__ __launch_bounds__(256) void k_prep(
        const float* __restrict__ W1, const float* __restrict__ W2,
        const float* __restrict__ W3, const float* __restrict__ W4,
        const float* __restrict__ W_in,
        u16* __restrict__ wt, float* __restrict__ partials,
        u32* __restrict__ bar) {
    int z = blockIdx.z;
    if (z == 4) {
        if (blockIdx.x >= 4 || blockIdx.y != 0) return;
        __shared__ float temb[128];
        int x = blockIdx.x, t = threadIdx.x;
        if (x == 0 && t < 8) bar[t] = 0u;
        if (t < 128) {
            int k = x * 128 + t;
            int p = k >> 1;
            float div = expf((float)(2 * p) * (-9.210340371976184f / 512.0f));
            temb[t] = (k & 1) ? cosf(49.0f * div) : sinf(49.0f * div);
        }
        __syncthreads();
#pragma unroll
        for (int half = 0; half < 2; ++half) {
            int col = half * 256 + t;
            float acc = 0.f;
            for (int kk = 0; kk < 128; ++kk)
                acc += temb[kk] * W_in[(size_t)(14 + x * 128 + kk) * HID + col];
            partials[x * HID + col] = acc;
        }
        return;
    }
    __shared__ float tile[32][33];
    const float* Ws[4] = {W1, W2, W3, W4};
    const float* W = Ws[z];
    u16* wh = wt + (size_t)z * 524288;
    u16* wl = wh + 262144;
    int kt = blockIdx.x * 32, nt = blockIdx.y * 32, t = threadIdx.x;
    int c = t & 31, r = t >> 5;
#pragma unroll
    for (int p = 0; p < 4; ++p)
        tile[r + p * 8][c] = W[(size_t)(kt + r + p * 8) * HID + nt + c];
    __syncthreads();
#pragma unroll
    for (int p = 0; p < 4; ++p) {
        int nl = r + p * 8, kl = c;
        float v = tile[kl][nl];
        u16 h = f2bf(v);
        u16 l2 = f2bf(v - bf2f(h));
        size_t o = fragoff(nt + nl, kt + kl);
        wh[o] = h;
        wl[o] = l2;
    }
}

// ---------------------------------------------------------------------------
// Grid barrier: ONE atomicAdd (RMW) per block at arrival; poll with a plain
// device-scope LOAD (round-6 post-mortem: RMW-polling serialized the L2
// atomic unit at ~46us/barrier; load-polling does not). s_sleep backoff.
// Deadlock-free: launch_bounds(512,4) caps VGPR<=128 -> 2 blocks/CU resident
// (LDS 96<=160KB, 16<=32 waves); grid = exactly 2*256.
// Replay-safe: slots zeroed by k_prep each launch; poll is "< target".
// ---------------------------------------------------------------------------
__device__ __forceinline__ void gbar(u32* bar, int i) {
    __syncthreads();
    if (threadIdx.x == 0) {
        __threadfence();                           // release: drain stores
        atomicAdd(&bar[i], 1u);                    // single RMW per block
        while (__hip_atomic_load(&bar[i], __ATOMIC_RELAXED,
                                 __HIP_MEMORY_SCOPE_AGENT) < (u32)NFB)
            __builtin_amdgcn_s_sleep(1);
        __threadfence();                           // acquire
    }
    __syncthreads();
}

// ---------------------------------------------------------------------------
// GEMM phase (device fn): EXACT round-10 interior. BM=BN=64, 8 waves, wave
// tile 16x32, BK=32, 3 slots, 2-deep prefetch, counted vmcnt (never 0
// in-loop), one s_barrier per step, setprio on MFMA, frag-layout 1KB staging.
// ---------------------------------------------------------------------------
__device__ __forceinline__ void gemm_phase(
        u16* lds,   // [3][4][4][512]
        const u16* __restrict__ Ah, const u16* __restrict__ Al,
        const u16* __restrict__ Wh, const u16* __restrict__ Wl,
        const float* __restrict__ bias,
        u16* __restrict__ Yh, u16* __restrict__ Yl,
        int m0, int n0, int lane, int w) {
    int wm = w >> 1, wn = w & 1;
    int p  = w >> 1;
    int g0 = (w & 1) * 2;
    const u16* pl = (p == 0) ? Ah : (p == 1) ? Al : (p == 2) ? Wh : Wl;
    int grpb = ((p < 2) ? m0 : n0) >> 4;
    const u16* src0 = pl + (size_t)((grpb + g0) * 16) * 512 + lane * 8;
    const u16* src1 = pl + (size_t)((grpb + g0 + 1) * 16) * 512 + lane * 8;

    auto slot = [&](int bb, int pp, int gg) -> u16* {
        return lds + (((bb * 4) + pp) * 4 + gg) * 512;
    };
    auto stage = [&](int c, int bb) {
        __builtin_amdgcn_global_load_lds(
            (const __attribute__((address_space(1))) void*)(src0 + c * 512),
            (__attribute__((address_space(3))) void*)slot(bb, p, g0), 16, 0, 0);
        __builtin_amdgcn_global_load_lds(
            (const __attribute__((address_space(1))) void*)(src1 + c * 512),
            (__attribute__((address_space(3))) void*)slot(bb, p, g0 + 1), 16, 0, 0);
    };

    f32x4 zero = {0.f, 0.f, 0.f, 0.f};
    f32x4 acc[2] = {zero, zero};

    stage(0, 0);
    stage(1, 1);
#pragma unroll
    for (int c = 0; c < 16; ++c) {
        int bb = c % 3;
        if (c < 15) { asm volatile("s_waitcnt vmcnt(2)" ::: "memory"); }
        else        { asm volatile("s_waitcnt vmcnt(0)" ::: "memory"); }
        __builtin_amdgcn_s_barrier();
        __builtin_amdgcn_sched_barrier(0);

        bf16x8 ah = *(const bf16x8*)(slot(bb, 0, wm) + lane * 8);
        bf16x8 al = *(const bf16x8*)(slot(bb, 1, wm) + lane * 8);
        bf16x8 bh[2], bl[2];
#pragma unroll
        for (int j = 0; j < 2; ++j) {
            bh[j] = *(const bf16x8*)(slot(bb, 2, wn * 2 + j) + lane * 8);
            bl[j] = *(const bf16x8*)(slot(bb, 3, wn * 2 + j) + lane * 8);
        }
        __builtin_amdgcn_s_setprio(1);
#pragma unroll
        for (int j = 0; j < 2; ++j) {
            acc[j] = __builtin_amdgcn_mfma_f32_16x16x32_bf16(ah, bh[j], acc[j], 0, 0, 0);
            acc[j] = __builtin_amdgcn_mfma_f32_16x16x32_bf16(ah, bl[j], acc[j], 0, 0, 0);
            acc[j] = __builtin_amdgcn_mfma_f32_16x16x32_bf16(al, bh[j], acc[j], 0, 0, 0);
        }
        __builtin_amdgcn_s_setprio(0);
        __builtin_amdgcn_sched_barrier(0);
        if (c < 14) stage(c + 2, (c + 2) % 3);
    }

    int row0 = m0 + wm * 16 + (lane >> 4) * 4;
#pragma unroll
    for (int j = 0; j < 2; ++j) {
        int col = n0 + wn * 32 + j * 16 + (lane & 15);
        float bia = bias[col];
#pragma unroll
        for (int r2 = 0; r2 < 4; ++r2) {
            float g = gelu_f(acc[j][r2] + bia);
            u16 hi = f2bf(g);
            size_t o = fragoff(row0 + r2, col);
            Yh[o] = hi;
            Yl[o] = f2bf(g - bf2f(hi));
        }
    }
}

__device__ void mat4mul(float C[4][4], const float A[4][4], const float Bm[4][4]) {
#pragma unroll
    for (int i = 0; i < 4; ++i)
#pragma unroll
        for (int j = 0; j < 4; ++j) {
            float s = A[i][0] * Bm[0][j];
            s += A[i][1] * Bm[1][j];
            s += A[i][2] * Bm[2][j];
            s += A[i][3] * Bm[3][j];
            C[i][j] = s;
        }
}

// ---------------------------------------------------------------------------
// K_fused: input layer + 4 GEMMs + output/FK/select in ONE kernel,
// separated by 5 load-poll grid barriers. Grid 512 x 512thr.
// Block bid: rows m0=(bid>>3)*64, cols n0=(bid&7)*64 for the GEMM phases;
// input phase computes exactly its own 64x64 tile (no duplication);
// tail: waves 0..3 handle batch elements bid*4..+3 (both steps each).
// ---------------------------------------------------------------------------
__global__ __launch_bounds__(512, 4) void k_fused(
        const float* __restrict__ x_pre, const float* __restrict__ noise,
        const float* __restrict__ W_in, const float* __restrict__ b_in,
        const float* __restrict__ partials, const u16* __restrict__ wt,
        const float* __restrict__ b1, const float* __restrict__ b2,
        const float* __restrict__ b3, const float* __restrict__ b4,
        const float* __restrict__ W_out, const float* __restrict__ b_out,
        u16* __restrict__ A0h, u16* __restrict__ A0l,
        u16* __restrict__ A1h, u16* __restrict__ A1l,
        u32* __restrict__ bar, float* __restrict__ out,
        float c1, float c2, float c3) {
    __shared__ __align__(16) u16 lds[3 * 4 * 4 * 512];   // 48 KB
    int tid = threadIdx.x, lane = tid & 63, w = tid >> 6;
    int bid = blockIdx.x;
    int m0 = (bid >> 3) * 64, n0 = (bid & 7) * 64;

    // ---- Phase 0: input layer, this block's 64 rows x 64 cols (once) ----
    {
        int r = tid >> 3;                 // 0..63 local row
        int row = m0 + r;
        int st = row >> 11, be = row & 2047;
        int nc = n0 + (tid & 7) * 8;      // col octet
        float xv[6], nz[8];
#pragma unroll
        for (int j = 0; j < 6; ++j) xv[j] = x_pre[be * 6 + j];
#pragma unroll
        for (int j = 0; j < 8; ++j) nz[j] = noise[(st * BATCH + be) * NACT + j];
        float acc[8];
#pragma unroll
        for (int q = 0; q < 2; ++q) {
            float4 bv = *(const float4*)&b_in[nc + q * 4];
            float4 p0 = *(const float4*)&partials[nc + q * 4];
            float4 p1 = *(const float4*)&partials[512 + nc + q * 4];
            float4 p2 = *(const float4*)&partials[1024 + nc + q * 4];
            float4 p3 = *(const float4*)&partials[1536 + nc + q * 4];
            acc[q * 4 + 0] = bv.x + p0.x + p1.x + p2.x + p3.x;
            acc[q * 4 + 1] = bv.y + p0.y + p1.y + p2.y + p3.y;
            acc[q * 4 + 2] = bv.z + p0.z + p1.z + p2.z + p3.z;
            acc[q * 4 + 3] = bv.w + p0.w + p1.w + p2.w + p3.w;
        }
#pragma unroll
        for (int j = 0; j < 14; ++j) {
            float xj = (j < 6) ? xv[j] : nz[j - 6];
            float4 wa = *(const float4*)&W_in[j * HID + nc];
            float4 wb = *(const float4*)&W_in[j * HID + nc + 4];
            acc[0] += xj * wa.x; acc[1] += xj * wa.y;
            acc[2] += xj * wa.z; acc[3] += xj * wa.w;
            acc[4] += xj * wb.x; acc[5] += xj * wb.y;
            acc[6] += xj * wb.z; acc[7] += xj * wb.w;
        }
        u16x8 hv, lv;
#pragma unroll
        for (int j2 = 0; j2 < 8; ++j2) {
            float g = gelu_f(acc[j2]);
            u16 hi = f2bf(g);
            hv[j2] = hi;
            lv[j2] = f2bf(g - bf2f(hi));
        }
        size_t o = fragoff(row, nc);
        *(u16x8*)&A0h[o] = hv;
        *(u16x8*)&A0l[o] = lv;
    }
    gbar(bar, 0);

    // ---- Phases 1..4 ----
    gemm_phase(lds, A0h, A0l, wt,                wt + 262144,           b1, A1h, A1l, m0, n0, lane, w);
    gbar(bar, 1);
    gemm_phase(lds, A1h, A1l, wt + 524288,       wt + 786432,           b2, A0h, A0l, m0, n0, lane, w);
    gbar(bar, 2);
    gemm_phase(lds, A0h, A0l, wt + 1048576,      wt + 1310720,          b3, A1h, A1l, m0, n0, lane, w);
    gbar(bar, 3);
    gemm_phase(lds, A1h, A1l, wt + 1572864,      wt + 1835008,          b4, A0h, A0l, m0, n0, lane, w);
    gbar(bar, 4);

    // ---- Phase 5: output layer + DDIM + tanh + FK + select -> d_out ----
    if (w < 4) {
        int b = bid * 4 + w;
        float acc0[8] = {0, 0, 0, 0, 0, 0, 0, 0};
        float acc1[8] = {0, 0, 0, 0, 0, 0, 0, 0};
#pragma unroll
        for (int it = 0; it < 8; ++it) {
            int k = lane + it * 64;
            size_t o0 = fragoff(b, k);
            size_t o1 = fragoff(BATCH + b, k);
            float ya = bf2f(A0h[o0]) + bf2f(A0l[o0]);
            float yb = bf2f(A0h[o1]) + bf2f(A0l[o1]);
            float4 w0 = ((const float4*)&W_out[k * NACT])[0];
            float4 w1 = ((const float4*)&W_out[k * NACT])[1];
            acc0[0] += ya * w0.x; acc0[1] += ya * w0.y; acc0[2] += ya * w0.z; acc0[3] += ya * w0.w;
            acc0[4] += ya * w1.x; acc0[5] += ya * w1.y; acc0[6] += ya * w1.z; acc0[7] += ya * w1.w;
            acc1[0] += yb * w0.x; acc1[1] += yb * w0.y; acc1[2] += yb * w0.z; acc1[3] += yb * w0.w;
            acc1[4] += yb * w1.x; acc1[5] += yb * w1.y; acc1[6] += yb * w1.z; acc1[7] += yb * w1.w;
        }
#pragma unroll
        for (int n = 0; n < 8; ++n) {
#pragma unroll
            for (int off = 32; off > 0; off >>= 1) {
                acc0[n] += __shfl_xor(acc0[n], off, 64);
                acc1[n] += __shfl_xor(acc1[n], off, 64);
            }
        }

        float jq[8] = {0, 0, 0, 0, 0, 0, 0, 0};
        float err = 0.f;
        if (lane < 2) {
            int s = lane;
            const float* accp = (s == 0) ? acc0 : acc1;
            const float HIf[8] = {
                (float)(35.0 * M_PI / 180.0), (float)(-60.0 * M_PI / 180.0), 3.94f,
                (float)(155.0 * M_PI / 180.0), (float)(-55.0 * M_PI / 180.0),
                (float)M_PI, (float)(5.0 * M_PI / 180.0), 3.71f};
            const float LOf[8] = {
                (float)(-35.0 * M_PI / 180.0), (float)(-155.0 * M_PI / 180.0), 2.59f,
                (float)(60.0 * M_PI / 180.0), (float)(-125.0 * M_PI / 180.0),
                (float)(-M_PI), (float)(-90.0 * M_PI / 180.0), 2.5f};
            const float* nzp = &noise[(s * BATCH + b) * NACT];
#pragma unroll
            for (int n = 0; n < 8; ++n) {
                float o = accp[n] + b_out[n];
                float z = c1 * nzp[n] + c2 * o + c3 * nzp[n];
                float jn = (tanhf(z * 0.1f) + 1.0f) * 0.5f;
                jq[n] = jn * (HIf[n] - LOf[n]) + LOf[n];
            }
            const float a_[8]  = {0.0f, 0.16f, 0.07f, 0.0f, 0.1334f, 0.0f, 0.15f, 0.3625f};
            const float ca_[8] = {1.f, 0.f, 0.f, 0.f, 0.f, 0.f, 0.f, 0.f};
            const float sa_[8] = {0.f, -1.f, -1.f, 1.f, -1.f, -1.f, 1.f, -1.f};
            float d_[8] = {0.0f, 0.0f, jq[2], 0.0f, -0.1316f, 1.0105f, 0.52f, jq[7]};
            float th[8] = {jq[0], jq[1], 0.0f, jq[3], jq[4], jq[5], jq[6], 0.0f};
            float T[4][4], M[4][4], Tn[4][4];
#pragma unroll
            for (int j = 0; j < 8; ++j) {
                float ct = cosf(th[j]);
                float st = sinf(th[j]);
                M[0][0] = ct;          M[0][1] = -st;         M[0][2] = 0.0f;    M[0][3] = a_[j];
                M[1][0] = st * ca_[j]; M[1][1] = ct * ca_[j]; M[1][2] = -sa_[j]; M[1][3] = -sa_[j] * d_[j];
                M[2][0] = st * sa_[j]; M[2][1] = ct * sa_[j]; M[2][2] = ca_[j];  M[2][3] = ca_[j] * d_[j];
                M[3][0] = 0.0f;        M[3][1] = 0.0f;        M[3][2] = 0.0f;    M[3][3] = 1.0f;
                if (j == 0) {
#pragma unroll
                    for (int i = 0; i < 4; ++i)
#pragma unroll
                        for (int cc = 0; cc < 4; ++cc) T[i][cc] = M[i][cc];
                } else {
                    mat4mul(Tn, T, M);
#pragma unroll
                    for (int i = 0; i < 4; ++i)
#pragma unroll
                        for (int cc = 0; cc < 4; ++cc) T[i][cc] = Tn[i][cc];
                }
            }
            float e1x = T[0][2] * 3.75f;
            float e1y = T[1][2] * 3.75f;
            float e1z = T[2][2] * 3.75f;
            float p0 = T[0][3];
            float p1 = T[1][3];
            float p2 = T[2][3] + 1.702f;
            float p3 = e1x + T[0][3];
            float p4 = e1y + T[1][3];
            float p5 = e1z + T[2][3] + 1.702f;
            const float* xp = &x_pre[b * 6];
            float dx0 = 100.0f * p0 - xp[0];
            float dx1 = 100.0f * p1 - xp[1];
            float dx2 = 100.0f * p2 - xp[2];
            float dx3 = 100.0f * p3 - xp[3];
            float dx4 = 100.0f * p4 - xp[4];
            float dx5 = 100.0f * p5 - xp[5];
            err = sqrtf(dx0 * dx0 + dx1 * dx1 + dx2 * dx2) +
                  sqrtf(dx3 * dx3 + dx4 * dx4 + dx5 * dx5);
        }
        float e0 = __shfl(err, 0, 64);
        float e1 = __shfl(err, 1, 64);
        int sel = (e1 < e0) ? 1 : 0;   // first index wins ties
        float jsel[8];
#pragma unroll
        for (int n = 0; n < 8; ++n) jsel[n] = __shfl(jq[n], sel, 64);
        if (lane == 0) {
#pragma unroll
            for (int n = 0; n < 8; ++n) out[b * NACT + n] = jsel[n];
        }
    }
}

// ===========================================================================
extern "C" void kernel_launch(void* const* d_in, const int* in_sizes, int n_in,
                              void* d_out, int out_size, void* d_ws, size_t ws_size,
                              hipStream_t stream) {
    const float* x_pre = (const float*)d_in[0];
    const float* noise = (const float*)d_in[1];
    const float* W_in  = (const float*)d_in[2];
    const float* b_in  = (const float*)d_in[3];
    const float* W1    = (const float*)d_in[4];
    const float* b1    = (const float*)d_in[5];
    const float* W2    = (const float*)d_in[6];
    const float* b2    = (const float*)d_in[7];
    const float* W3    = (const float*)d_in[8];
    const float* b3    = (const float*)d_in[9];
    const float* W4    = (const float*)d_in[10];
    const float* b4    = (const float*)d_in[11];
    const float* W_out = (const float*)d_in[12];
    const float* b_out = (const float*)d_in[13];

    // DDIM last-step coefficients (only the last loop iteration matters:
    // z is overwritten every iteration in the reference, nz never updated).
    double ab_c = exp(-0.1 * 50.0 / 1000.0 - 0.5 * (10.0 - 0.1) * 2500.0 / 1.0e6);
    float c1 = (float)sqrt(1.0 / ab_c);
    float c2 = (float)(-sqrt((1.0 - ab_c) / ab_c));
    float c3 = (float)sqrt(1.0 - ab_c);

    char* base = (char*)d_ws;
    u16* A0h = (u16*)base;                       // activation planes, 4 MB each
    u16* A0l = A0h + 2097152;
    u16* A1h = A0l + 2097152;
    u16* A1l = A1h + 2097152;
    u16* wt  = (u16*)(base + 16777216);          // 4 layers x (hi,lo) frag planes
    float* partials = (float*)(base + 16777216 + 4194304); // 4x512
    u32* bar = (u32*)(partials + 2048);          // 8 barrier slots

    k_prep<<<dim3(16, 16, 5), 256, 0, stream>>>(W1, W2, W3, W4, W_in,
                                                wt, partials, bar);
    k_fused<<<NFB, 512, 0, stream>>>(x_pre, noise, W_in, b_in, partials, wt,
                                     b1, b2, b3, b4, W_out, b_out,
                                     A0h, A0l, A1h, A1l, bar, (float*)d_out,
                                     c1, c2, c3);
}

// Round 15
// 87.476 us; speedup vs baseline: 4.8875x; 4.8875x over previous
//
#include <hip/hip_runtime.h>
#include <math.h>

typedef __bf16 bf16x8 __attribute__((ext_vector_type(8)));
typedef float f32x4 __attribute__((ext_vector_type(4)));
typedef unsigned short u16;
typedef unsigned short u16x8 __attribute__((ext_vector_type(8)));
typedef unsigned int u32;

constexpr int BATCH = 2048;
constexpr int ROWS  = 4096;   // 2 steps x 2048
constexpr int HID   = 512;
constexpr int NACT  = 8;

__device__ __forceinline__ float gelu_f(float x) {
    return 0.5f * x * (1.0f + erff(x * 0.70710678118654752f));
}
__device__ __forceinline__ u16 f2bf(float f) {
    u32 u = __float_as_uint(f);
    return (u16)((u + 0x7FFFu + ((u >> 16) & 1u)) >> 16);
}
__device__ __forceinline__ float bf2f(u16 h) {
    return __uint_as_float(((u32)h) << 16);
}

// Fragment-chunk layout for every bf16 plane:
//   plane[(r>>4)*16 + (k>>5)][512], idx = (((k&31)>>3)*16 + (r&15))*8 + (k&7)
// A 16-row x 32-k tile is one contiguous 1KB block in exact MFMA-fragment
// lane order -> staging loads are single contiguous 1KB bursts.
__device__ __forceinline__ size_t fragoff(int r, int k) {
    return (size_t)(((r >> 4) * 16 + (k >> 5)) * 512
                    + (((k & 31) >> 3) * 16 + (r & 15)) * 8 + (k & 7));
}

// ---------------------------------------------------------------------------
// K_prep: x<16 -> transpose + hi/lo-split weight layer z into wt (frag layout)
//         x==16 && z==0 && y<4 -> partials[y] = temb-slice @ W_in slice (no
//         cross-block reduction: summed by consumers; deterministic).
// Grid (17,16,4): the partials work rides in the x=16 column of slice z=0
// (round-14 ledger: the old dedicated z=4 slice was 256 mostly-idle blocks).
// ---------------------------------------------------------------------------
__global__ __launch_bounds__(256) void k_prep(
        const float* __restrict__ W1, const float* __restrict__ W2,
        const float* __restrict__ W3, const float* __restrict__ W4,
        const float* __restrict__ W_in,
        u16* __restrict__ wt, float* __restrict__ partials) {
    int z = blockIdx.z;
    if (blockIdx.x == 16) {
        if (z != 0 || blockIdx.y >= 4) return;
        __shared__ float temb[128];
        int x = blockIdx.y, t = threadIdx.x;
        if (t < 128) {
            int k = x * 128 + t;
            int p = k >> 1;
            float div = expf((float)(2 * p) * (-9.210340371976184f / 512.0f));
            temb[t] = (k & 1) ? cosf(49.0f * div) : sinf(49.0f * div);
        }
        __syncthreads();
#pragma unroll
        for (int half = 0; half < 2; ++half) {
            int col = half * 256 + t;
            float acc = 0.f;
            for (int kk = 0; kk < 128; ++kk)
                acc += temb[kk] * W_in[(size_t)(14 + x * 128 + kk) * HID + col];
            partials[x * HID + col] = acc;
        }
        return;
    }
    __shared__ float tile[32][33];
    const float* Ws[4] = {W1, W2, W3, W4};
    const float* W = Ws[z];
    u16* wh = wt + (size_t)z * 524288;
    u16* wl = wh + 262144;
    int kt = blockIdx.x * 32, nt = blockIdx.y * 32, t = threadIdx.x;
    int c = t & 31, r = t >> 5;
#pragma unroll
    for (int p = 0; p < 4; ++p)
        tile[r + p * 8][c] = W[(size_t)(kt + r + p * 8) * HID + nt + c];
    __syncthreads();
#pragma unroll
    for (int p = 0; p < 4; ++p) {
        int nl = r + p * 8, kl = c;
        float v = tile[kl][nl];
        u16 h = f2bf(v);
        u16 l2 = f2bf(v - bf2f(h));
        size_t o = fragoff(nt + nl, kt + kl);
        wh[o] = h;
        wl[o] = l2;
    }
}

// ---------------------------------------------------------------------------
// K_layer_in: input layer, each element computed once. One wave per row;
// lane o computes col-octet o: float4 weight loads, u16x8 frag stores.
// ---------------------------------------------------------------------------
__global__ __launch_bounds__(256) void k_layer_in(
        const float* __restrict__ x_pre, const float* __restrict__ noise,
        const float* __restrict__ W_in, const float* __restrict__ b_in,
        const float* __restrict__ partials,
        u16* __restrict__ Yh, u16* __restrict__ Yl) {
    int id = blockIdx.x * 256 + threadIdx.x;
    int r = id >> 6, oct = id & 63;
    int s = r >> 11, bidx = r & 2047;
    float xv[6], nz[8];
#pragma unroll
    for (int j = 0; j < 6; ++j) xv[j] = x_pre[bidx * 6 + j];
#pragma unroll
    for (int j = 0; j < 8; ++j) nz[j] = noise[(s * BATCH + bidx) * NACT + j];
    int nc = oct * 8;
    float acc[8];
#pragma unroll
    for (int q = 0; q < 2; ++q) {
        float4 bv = *(const float4*)&b_in[nc + q * 4];
        float4 p0 = *(const float4*)&partials[nc + q * 4];
        float4 p1 = *(const float4*)&partials[512 + nc + q * 4];
        float4 p2 = *(const float4*)&partials[1024 + nc + q * 4];
        float4 p3 = *(const float4*)&partials[1536 + nc + q * 4];
        acc[q * 4 + 0] = bv.x + p0.x + p1.x + p2.x + p3.x;
        acc[q * 4 + 1] = bv.y + p0.y + p1.y + p2.y + p3.y;
        acc[q * 4 + 2] = bv.z + p0.z + p1.z + p2.z + p3.z;
        acc[q * 4 + 3] = bv.w + p0.w + p1.w + p2.w + p3.w;
    }
#pragma unroll
    for (int j = 0; j < 14; ++j) {
        float xj = (j < 6) ? xv[j] : nz[j - 6];
        float4 wa = *(const float4*)&W_in[j * HID + nc];
        float4 wb = *(const float4*)&W_in[j * HID + nc + 4];
        acc[0] += xj * wa.x; acc[1] += xj * wa.y;
        acc[2] += xj * wa.z; acc[3] += xj * wa.w;
        acc[4] += xj * wb.x; acc[5] += xj * wb.y;
        acc[6] += xj * wb.z; acc[7] += xj * wb.w;
    }
    u16x8 hv, lv;
#pragma unroll
    for (int j2 = 0; j2 < 8; ++j2) {
        float g = gelu_f(acc[j2]);
        u16 hi = f2bf(g);
        hv[j2] = hi;
        lv[j2] = f2bf(g - bf2f(hi));
    }
    size_t o = fragoff(r, nc);
    *(u16x8*)&Yh[o] = hv;
    *(u16x8*)&Yl[o] = lv;
}

// ---------------------------------------------------------------------------
// G1..G4: proven counted-vmcnt pipeline + frag-layout staging (1KB bursts).
// BM=BN=64, 8 waves, wave tile 16x32, BK=32, 3 slots, 2-deep prefetch,
// counted vmcnt (never 0 in-loop), one s_barrier per step, setprio on MFMA.
// (Round-10 configuration — empirical optimum across rounds 3..14.)
// ---------------------------------------------------------------------------
__global__ __launch_bounds__(512) void k_gemm_f(
        const u16* __restrict__ Ah, const u16* __restrict__ Al,
        const u16* __restrict__ Wh, const u16* __restrict__ Wl,
        const float* __restrict__ bias,
        u16* __restrict__ Yh, u16* __restrict__ Yl) {
    __shared__ __align__(16) u16 lds[3][4][4][512];   // 48 KB
    int tid = threadIdx.x, lane = tid & 63, w = tid >> 6;
    int wm = w >> 1, wn = w & 1;
    int m0 = blockIdx.x * 64, n0 = blockIdx.y * 64;

    int p  = w >> 1;            // plane: Ah,Al,Wh,Wl for wave pairs
    int g0 = (w & 1) * 2;       // two 16-row groups per wave
    const u16* pl = (p == 0) ? Ah : (p == 1) ? Al : (p == 2) ? Wh : Wl;
    int grpb = ((p < 2) ? m0 : n0) >> 4;
    const u16* src0 = pl + (size_t)((grpb + g0) * 16) * 512 + lane * 8;
    const u16* src1 = pl + (size_t)((grpb + g0 + 1) * 16) * 512 + lane * 8;

    auto stage = [&](int c, int bb) {
        __builtin_amdgcn_global_load_lds(
            (const __attribute__((address_space(1))) void*)(src0 + c * 512),
            (__attribute__((address_space(3))) void*)&lds[bb][p][g0][0], 16, 0, 0);
        __builtin_amdgcn_global_load_lds(
            (const __attribute__((address_space(1))) void*)(src1 + c * 512),
            (__attribute__((address_space(3))) void*)&lds[bb][p][g0 + 1][0], 16, 0, 0);
    };

    f32x4 zero = {0.f, 0.f, 0.f, 0.f};
    f32x4 acc[2] = {zero, zero};

    stage(0, 0);
    stage(1, 1);
#pragma unroll
    for (int c = 0; c < 16; ++c) {
        int bb = c % 3;
        if (c < 15) { asm volatile("s_waitcnt vmcnt(2)" ::: "memory"); }
        else        { asm volatile("s_waitcnt vmcnt(0)" ::: "memory"); }
        __builtin_amdgcn_s_barrier();
        __builtin_amdgcn_sched_barrier(0);

        bf16x8 ah = *(const bf16x8*)&lds[bb][0][wm][lane * 8];
        bf16x8 al = *(const bf16x8*)&lds[bb][1][wm][lane * 8];
        bf16x8 bh[2], bl[2];
#pragma unroll
        for (int j = 0; j < 2; ++j) {
            bh[j] = *(const bf16x8*)&lds[bb][2][wn * 2 + j][lane * 8];
            bl[j] = *(const bf16x8*)&lds[bb][3][wn * 2 + j][lane * 8];
        }
        __builtin_amdgcn_s_setprio(1);
#pragma unroll
        for (int j = 0; j < 2; ++j) {
            acc[j] = __builtin_amdgcn_mfma_f32_16x16x32_bf16(ah, bh[j], acc[j], 0, 0, 0);
            acc[j] = __builtin_amdgcn_mfma_f32_16x16x32_bf16(ah, bl[j], acc[j], 0, 0, 0);
            acc[j] = __builtin_amdgcn_mfma_f32_16x16x32_bf16(al, bh[j], acc[j], 0, 0, 0);
        }
        __builtin_amdgcn_s_setprio(0);
        __builtin_amdgcn_sched_barrier(0);
        if (c < 14) stage(c + 2, (c + 2) % 3);   // overwrites slot (c-1)%3: its
                                                 // readers passed this step's barrier
    }

    int row0 = m0 + wm * 16 + (lane >> 4) * 4;
#pragma unroll
    for (int j = 0; j < 2; ++j) {
        int col = n0 + wn * 32 + j * 16 + (lane & 15);
        float bia = bias[col];
#pragma unroll
        for (int r2 = 0; r2 < 4; ++r2) {
            float g = gelu_f(acc[j][r2] + bia);
            u16 hi = f2bf(g);
            size_t o = fragoff(row0 + r2, col);
            Yh[o] = hi;
            Yl[o] = f2bf(g - bf2f(hi));
        }
    }
}

// ---------------------------------------------------------------------------
// out_fk: output layer for BOTH steps + DDIM + tanh + FK + select -> d_out.
// One wave per batch element; lanes 0/1 run FK for step 0/1 in parallel.
// ---------------------------------------------------------------------------
__device__ void mat4mul(float C[4][4], const float A[4][4], const float Bm[4][4]) {
#pragma unroll
    for (int i = 0; i < 4; ++i)
#pragma unroll
        for (int j = 0; j < 4; ++j) {
            float s = A[i][0] * Bm[0][j];
            s += A[i][1] * Bm[1][j];
            s += A[i][2] * Bm[2][j];
            s += A[i][3] * Bm[3][j];
            C[i][j] = s;
        }
}

__global__ __launch_bounds__(256) void k_out_fk(
        const u16* __restrict__ Yh, const u16* __restrict__ Yl,
        const float* __restrict__ W_out, const float* __restrict__ b_out,
        const float* __restrict__ noise, const float* __restrict__ x_pre,
        float* __restrict__ out, float c1, float c2, float c3) {
    int b = blockIdx.x * 4 + (threadIdx.x >> 6);
    int lane = threadIdx.x & 63;

    float acc0[8] = {0, 0, 0, 0, 0, 0, 0, 0};
    float acc1[8] = {0, 0, 0, 0, 0, 0, 0, 0};
#pragma unroll
    for (int it = 0; it < 8; ++it) {
        int k = lane + it * 64;
        size_t o0 = fragoff(b, k);
        size_t o1 = fragoff(BATCH + b, k);
        float ya = bf2f(Yh[o0]) + bf2f(Yl[o0]);
        float yb = bf2f(Yh[o1]) + bf2f(Yl[o1]);
        float4 w0 = ((const float4*)&W_out[k * NACT])[0];
        float4 w1 = ((const float4*)&W_out[k * NACT])[1];
        acc0[0] += ya * w0.x; acc0[1] += ya * w0.y; acc0[2] += ya * w0.z; acc0[3] += ya * w0.w;
        acc0[4] += ya * w1.x; acc0[5] += ya * w1.y; acc0[6] += ya * w1.z; acc0[7] += ya * w1.w;
        acc1[0] += yb * w0.x; acc1[1] += yb * w0.y; acc1[2] += yb * w0.z; acc1[3] += yb * w0.w;
        acc1[4] += yb * w1.x; acc1[5] += yb * w1.y; acc1[6] += yb * w1.z; acc1[7] += yb * w1.w;
    }
#pragma unroll
    for (int n = 0; n < 8; ++n) {
#pragma unroll
        for (int off = 32; off > 0; off >>= 1) {
            acc0[n] += __shfl_xor(acc0[n], off, 64);
            acc1[n] += __shfl_xor(acc1[n], off, 64);
        }
    }

    float jq[8] = {0, 0, 0, 0, 0, 0, 0, 0};
    float err = 0.f;
    if (lane < 2) {
        int s = lane;
        const float* accp = (s == 0) ? acc0 : acc1;
        const float HIf[8] = {
            (float)(35.0 * M_PI / 180.0), (float)(-60.0 * M_PI / 180.0), 3.94f,
            (float)(155.0 * M_PI / 180.0), (float)(-55.0 * M_PI / 180.0),
            (float)M_PI, (float)(5.0 * M_PI / 180.0), 3.71f};
        const float LOf[8] = {
            (float)(-35.0 * M_PI / 180.0), (float)(-155.0 * M_PI / 180.0), 2.59f,
            (float)(60.0 * M_PI / 180.0), (float)(-125.0 * M_PI / 180.0),
            (float)(-M_PI), (float)(-90.0 * M_PI / 180.0), 2.5f};
        const float* nzp = &noise[(s * BATCH + b) * NACT];
#pragma unroll
        for (int n = 0; n < 8; ++n) {
            float o = accp[n] + b_out[n];
            float z = c1 * nzp[n] + c2 * o + c3 * nzp[n];
            float jn = (tanhf(z * 0.1f) + 1.0f) * 0.5f;
            jq[n] = jn * (HIf[n] - LOf[n]) + LOf[n];
        }
        const float a_[8]  = {0.0f, 0.16f, 0.07f, 0.0f, 0.1334f, 0.0f, 0.15f, 0.3625f};
        const float ca_[8] = {1.f, 0.f, 0.f, 0.f, 0.f, 0.f, 0.f, 0.f};
        const float sa_[8] = {0.f, -1.f, -1.f, 1.f, -1.f, -1.f, 1.f, -1.f};
        float d_[8] = {0.0f, 0.0f, jq[2], 0.0f, -0.1316f, 1.0105f, 0.52f, jq[7]};
        float th[8] = {jq[0], jq[1], 0.0f, jq[3], jq[4], jq[5], jq[6], 0.0f};
        float T[4][4], M[4][4], Tn[4][4];
#pragma unroll
        for (int j = 0; j < 8; ++j) {
            float ct = cosf(th[j]);
            float st = sinf(th[j]);
            M[0][0] = ct;          M[0][1] = -st;         M[0][2] = 0.0f;    M[0][3] = a_[j];
            M[1][0] = st * ca_[j]; M[1][1] = ct * ca_[j]; M[1][2] = -sa_[j]; M[1][3] = -sa_[j] * d_[j];
            M[2][0] = st * sa_[j]; M[2][1] = ct * sa_[j]; M[2][2] = ca_[j];  M[2][3] = ca_[j] * d_[j];
            M[3][0] = 0.0f;        M[3][1] = 0.0f;        M[3][2] = 0.0f;    M[3][3] = 1.0f;
            if (j == 0) {
#pragma unroll
                for (int i = 0; i < 4; ++i)
#pragma unroll
                    for (int cc = 0; cc < 4; ++cc) T[i][cc] = M[i][cc];
            } else {
                mat4mul(Tn, T, M);
#pragma unroll
                for (int i = 0; i < 4; ++i)
#pragma unroll
                    for (int cc = 0; cc < 4; ++cc) T[i][cc] = Tn[i][cc];
            }
        }
        float e1x = T[0][2] * 3.75f;
        float e1y = T[1][2] * 3.75f;
        float e1z = T[2][2] * 3.75f;
        float p0 = T[0][3];
        float p1 = T[1][3];
        float p2 = T[2][3] + 1.702f;
        float p3 = e1x + T[0][3];
        float p4 = e1y + T[1][3];
        float p5 = e1z + T[2][3] + 1.702f;
        const float* xp = &x_pre[b * 6];
        float dx0 = 100.0f * p0 - xp[0];
        float dx1 = 100.0f * p1 - xp[1];
        float dx2 = 100.0f * p2 - xp[2];
        float dx3 = 100.0f * p3 - xp[3];
        float dx4 = 100.0f * p4 - xp[4];
        float dx5 = 100.0f * p5 - xp[5];
        err = sqrtf(dx0 * dx0 + dx1 * dx1 + dx2 * dx2) +
              sqrtf(dx3 * dx3 + dx4 * dx4 + dx5 * dx5);
    }
    float e0 = __shfl(err, 0, 64);
    float e1 = __shfl(err, 1, 64);
    int sel = (e1 < e0) ? 1 : 0;   // first index wins ties
    float jsel[8];
#pragma unroll
    for (int n = 0; n < 8; ++n) jsel[n] = __shfl(jq[n], sel, 64);
    if (lane == 0) {
#pragma unroll
        for (int n = 0; n < 8; ++n) out[b * NACT + n] = jsel[n];
    }
}

// ===========================================================================
extern "C" void kernel_launch(void* const* d_in, const int* in_sizes, int n_in,
                              void* d_out, int out_size, void* d_ws, size_t ws_size,
                              hipStream_t stream) {
    const float* x_pre = (const float*)d_in[0];
    const float* noise = (const float*)d_in[1];
    const float* W_in  = (const float*)d_in[2];
    const float* b_in  = (const float*)d_in[3];
    const float* W1    = (const float*)d_in[4];
    const float* b1    = (const float*)d_in[5];
    const float* W2    = (const float*)d_in[6];
    const float* b2    = (const float*)d_in[7];
    const float* W3    = (const float*)d_in[8];
    const float* b3    = (const float*)d_in[9];
    const float* W4    = (const float*)d_in[10];
    const float* b4    = (const float*)d_in[11];
    const float* W_out = (const float*)d_in[12];
    const float* b_out = (const float*)d_in[13];

    // DDIM last-step coefficients (only the last loop iteration matters:
    // z is overwritten every iteration in the reference, nz never updated).
    double ab_c = exp(-0.1 * 50.0 / 1000.0 - 0.5 * (10.0 - 0.1) * 2500.0 / 1.0e6);
    float c1 = (float)sqrt(1.0 / ab_c);
    float c2 = (float)(-sqrt((1.0 - ab_c) / ab_c));
    float c3 = (float)sqrt(1.0 - ab_c);

    char* base = (char*)d_ws;
    u16* Ah = (u16*)base;                        // 4 activation planes, 4 MB each
    u16* Al = Ah + 2097152;
    u16* Bh = Al + 2097152;
    u16* Bl = Bh + 2097152;
    u16* wt = (u16*)(base + 16777216);           // 4 layers x (hi,lo) frag planes
    float* partials = (float*)(base + 16777216 + 4194304); // 4x512

    k_prep<<<dim3(17, 16, 4), 256, 0, stream>>>(W1, W2, W3, W4, W_in, wt, partials);
    k_layer_in<<<ROWS * 64 / 256, 256, 0, stream>>>(x_pre, noise, W_in, b_in,
                                                    partials, Ah, Al);
    dim3 g(ROWS / 64, HID / 64);
    k_gemm_f<<<g, 512, 0, stream>>>(Ah, Al, wt + 0 * 524288, wt + 0 * 524288 + 262144, b1, Bh, Bl);
    k_gemm_f<<<g, 512, 0, stream>>>(Bh, Bl, wt + 1 * 524288, wt + 1 * 524288 + 262144, b2, Ah, Al);
    k_gemm_f<<<g, 512, 0, stream>>>(Ah, Al, wt + 2 * 524288, wt + 2 * 524288 + 262144, b3, Bh, Bl);
    k_gemm_f<<<g, 512, 0, stream>>>(Bh, Bl, wt + 3 * 524288, wt + 3 * 524288 + 262144, b4, Ah, Al);
    k_out_fk<<<BATCH / 4, 256, 0, stream>>>(Ah, Al, W_out, b_out, noise, x_pre,
                                            (float*)d_out, c1, c2, c3);
}